// Round 1
// 413.531 us; speedup vs baseline: 1.0217x; 1.0217x over previous
//
#include <hip/hip_runtime.h>

// TreeLRU: B=16, N=4095 heap, IN=OUT=512, S=256.
// Round 5: (1) GEMM K-loop double-buffered (T3 minimum 2-phase): prefetch
// next K-tile via global_load_lds into buf^1 while computing buf, one
// vmcnt(0)+barrier per tile (from __syncthreads) instead of a serial
// load->drain->compute per tile. LDS 32->64KB. (2) cvt + prep_M + prep_C
// + prep_bias merged into one launch (blockIdx-range dispatch) so the
// small prep kernels hide under cvt's 201MB of traffic.

#define ROWS 65520
#define KDIM 512

typedef __attribute__((ext_vector_type(8))) short bf16x8;
typedef __attribute__((ext_vector_type(4))) float f32x4;

__device__ __forceinline__ unsigned short f2bf(float f) {
    unsigned int u = __float_as_uint(f);
    unsigned int r = (u + 0x7FFFu + ((u >> 16) & 1u)) >> 16;
    return (unsigned short)r;
}
__device__ __forceinline__ float b2f(unsigned short h) {
    return __uint_as_float(((unsigned int)h) << 16);
}

// ---------------- merged prep: cvt | prep_M | prep_C | prep_bias ----------------
// cvt:      blocks [0, 32760)   x f32 -> bf16, float4 per thread
// prep_M:   blocks [32760, 33784)  M = (Bsel * gamma) @ W, f32 math, bf16 out
// prep_C:   blocks [33784, 34808)  C16 = [Cre | -Cim] bf16
// prep_bias:blocks [34808, 34936)  biasc[c] = gamma_c * <b_in, Bsel_c>, 4 ch/block
#define CVT_BLKS  32760
#define PM_BASE   32760
#define PC_BASE   33784
#define PB_BASE   34808
#define PREP_GRID 34936

__global__ __launch_bounds__(256) void prep_all(const float* __restrict__ x,
                                                unsigned short* __restrict__ x16,
                                                const float* __restrict__ W,
                                                const float* __restrict__ Bre,
                                                const float* __restrict__ Bim,
                                                const float* __restrict__ gamma_log,
                                                unsigned short* __restrict__ M16,
                                                const float* __restrict__ bin,
                                                float* __restrict__ biasc,
                                                const float* __restrict__ Cre,
                                                const float* __restrict__ Cim,
                                                unsigned short* __restrict__ C16) {
    __shared__ float Bs[16][17];
    __shared__ float Ws[16][17];
    const int blk = blockIdx.x;
    const int t = threadIdx.x;

    if (blk < CVT_BLKS) {
        // ---- cvt f32 -> bf16, 4 elems/thread ----
        int i = blk * 256 + t;   // n4 = 8386560 = 32760*256 exactly
        float4 v = ((const float4*)x)[i];
        ushort4 o;
        o.x = f2bf(v.x); o.y = f2bf(v.y); o.z = f2bf(v.z); o.w = f2bf(v.w);
        ((ushort4*)x16)[i] = o;
    } else if (blk < PC_BASE) {
        // ---- prep_M: 32x32 grid of 16x16 tiles ----
        const int pm = blk - PM_BASE;
        const int bx = pm & 31;        // j tile
        const int by = pm >> 5;        // cc tile
        const int tx = t & 15;
        const int ty = t >> 4;
        const int j  = bx * 16 + tx;
        const int cc = by * 16 + ty;
        const float* Bsel = (cc < 256) ? (Bre + (size_t)cc * 512)
                                       : (Bim + (size_t)(cc - 256) * 512);
        float acc = 0.f;
        for (int kt = 0; kt < 512; kt += 16) {
            Bs[ty][tx] = Bsel[kt + tx];
            Ws[ty][tx] = W[(size_t)(kt + ty) * 512 + j];
            __syncthreads();
#pragma unroll
            for (int k = 0; k < 16; ++k) acc += Bs[ty][k] * Ws[k][tx];
            __syncthreads();
        }
        float g = expf(gamma_log[cc & 255]);
        M16[(size_t)cc * 512 + j] = f2bf(acc * g);
    } else if (blk < PB_BASE) {
        // ---- prep_C ----
        int idx = (blk - PC_BASE) * 256 + t;   // 0..262143
        int o = idx >> 9;
        int s = idx & 511;
        float v = (s < 256) ? Cre[(size_t)o * 256 + s] : -Cim[(size_t)o * 256 + (s - 256)];
        C16[idx] = f2bf(v);
    } else {
        // ---- prep_bias: 4 channels per block, one wave each ----
        const int c = (blk - PB_BASE) * 4 + (t >> 6);   // 0..511
        const int lane = t & 63;
        const float* Bsel = (c < 256) ? (Bre + (size_t)c * 512)
                                      : (Bim + (size_t)(c - 256) * 512);
        float acc = 0.f;
#pragma unroll
        for (int i = lane; i < 512; i += 64) acc += bin[i] * Bsel[i];
#pragma unroll
        for (int off = 32; off > 0; off >>= 1) acc += __shfl_down(acc, off, 64);
        if (lane == 0) biasc[c] = acc * expf(gamma_log[c & 255]);
    }
}

// ---------------- bf16 MFMA GEMM: C = A @ B^T (+bias), K=N=512 ----------------
// 128x128 block tile, 4 waves, each wave 64x64 (4x4 of 16x16x32 MFMA), BK=64.
// Double-buffered LDS (2x32KB): iteration t prefetches tile t+1 into buf^1
// while the MFMAs consume buf. __syncthreads at the bottom of each iter
// supplies the vmcnt(0)+lgkmcnt(0)+s_barrier that publishes the prefetch.
// XCD-aware swizzle: xcd = bid&7; each XCD owns 64 row-tiles x 4 col-tiles
// with the 4 A-sharing siblings adjacent in dispatch order.
template <bool OUT_BF16>
__global__ __launch_bounds__(256) void gemm_mfma(const unsigned short* __restrict__ A,
                                                 const unsigned short* __restrict__ Bm,
                                                 const float* __restrict__ bias,
                                                 void* __restrict__ Cout,
                                                 int Mrows) {
    __shared__ __align__(16) unsigned short As[2][128 * 64];
    __shared__ __align__(16) unsigned short Bs[2][128 * 64];
    const int t = threadIdx.x;
    const int lane = t & 63;
    const int w = t >> 6;
    const int wr = (w >> 1) * 64;
    const int wc = (w & 1) * 64;
    const int bid = blockIdx.x;
    const int xcd = bid & 7;
    const int lid = bid >> 3;               // 0..255
    const int rowblk = xcd * 64 + (lid >> 2);
    const int colblk = lid & 3;
    const int row0 = rowblk * 128;
    const int col0 = colblk * 128;
    const int kt0  = (rowblk & 7) * 64;

    f32x4 acc[4][4] = {};

    // stage K-tile `it` into buffer `pb` (8 global_load_lds x 16B per thread)
#define STAGE(pb, itv)                                                         \
    do {                                                                       \
        const int kt_ = (kt0 + (itv) * 64) & 511;                              \
        _Pragma("unroll")                                                      \
        for (int q = 0; q < 4; ++q) {                                          \
            int c_   = q * 256 + t;                                            \
            int row_ = c_ >> 3;                                                \
            int kc_  = c_ & 7;                                                 \
            int kg_  = kc_ ^ (row_ & 7);                                       \
            int ar_  = row0 + row_; if (ar_ >= Mrows) ar_ = Mrows - 1;         \
            const unsigned short* ga_ = A + (size_t)ar_ * KDIM + kt_ + kg_ * 8;\
            __builtin_amdgcn_global_load_lds(                                  \
                (const __attribute__((address_space(1))) unsigned int*)ga_,    \
                (__attribute__((address_space(3))) unsigned int*)(&As[pb][c_ * 8]),\
                16, 0, 0);                                                     \
            const unsigned short* gb_ = Bm + (size_t)(col0 + row_) * KDIM + kt_ + kg_ * 8;\
            __builtin_amdgcn_global_load_lds(                                  \
                (const __attribute__((address_space(1))) unsigned int*)gb_,    \
                (__attribute__((address_space(3))) unsigned int*)(&Bs[pb][c_ * 8]),\
                16, 0, 0);                                                     \
        }                                                                      \
    } while (0)

    STAGE(0, 0);
    __syncthreads();        // drains vmcnt(0): tile 0 resident

    int cur = 0;
    for (int it = 0; it < 8; ++it) {
        if (it < 7) STAGE(cur ^ 1, it + 1);   // prefetch next tile (overlaps MFMA)
#pragma unroll
        for (int kk = 0; kk < 64; kk += 32) {
            const int kgc = kk >> 3;  // 0 or 4
            bf16x8 af[4], bfr[4];
#pragma unroll
            for (int i = 0; i < 4; ++i) {
                int row = wr + i * 16 + (lane & 15);
                int kca = (kgc + (lane >> 4)) ^ (row & 7);
                af[i] = *(const bf16x8*)(&As[cur][row * 64 + kca * 8]);
                int colr = wc + i * 16 + (lane & 15);
                int kcb = (kgc + (lane >> 4)) ^ (colr & 7);
                bfr[i] = *(const bf16x8*)(&Bs[cur][colr * 64 + kcb * 8]);
            }
#pragma unroll
            for (int i = 0; i < 4; ++i)
#pragma unroll
                for (int j = 0; j < 4; ++j)
                    acc[i][j] = __builtin_amdgcn_mfma_f32_16x16x32_bf16(
                        af[i], bfr[j], acc[i][j], 0, 0, 0);
        }
        __syncthreads();    // vmcnt(0)+barrier: publishes prefetched tile
        cur ^= 1;
    }
#undef STAGE

    // epilogue: C/D layout col=lane&15, row=(lane>>4)*4+reg  [m89/m91 verified]
    const int cq = lane >> 4;
    const int cl = lane & 15;
#pragma unroll
    for (int i = 0; i < 4; ++i) {
#pragma unroll
        for (int j = 0; j < 4; ++j) {
#pragma unroll
            for (int r = 0; r < 4; ++r) {
                int grow = row0 + wr + i * 16 + cq * 4 + r;
                int gcol = col0 + wc + j * 16 + cl;
                if (grow < Mrows) {
                    float v = acc[i][j][r];
                    if (bias) v += bias[gcol];
                    if (OUT_BF16)
                        ((unsigned short*)Cout)[(size_t)grow * 512 + gcol] = f2bf(v);
                    else
                        ((float*)Cout)[(size_t)grow * 512 + gcol] = v;
                }
            }
        }
    }
}

// ---------------- tree recurrence: register-resident subtree, loads up-front.
// Block (b, s): subtree rooted at node root_base+s. E levels below the root
// are loaded as "leaf" children (already-final h values); the E levels
// root..root+E-1 are computed in fp32 registers and stored (bf16) once.
// Thread c owns channel c (re at col c, im at col 256+c). No syncs needed.
template <int E>
__global__ __launch_bounds__(256) void tree_up(unsigned short* __restrict__ buf,
                                               const float* __restrict__ nu_log,
                                               const float* __restrict__ theta_log,
                                               int root_base) {
    const int b = blockIdx.x;
    const int rs = root_base + blockIdx.y;
    const int c = threadIdx.x;
    constexpr int LEAVES = 1 << E;
    const float lam = expf(-expf(nu_log[c]));
    const float th  = expf(theta_log[c]);
    const float lr  = lam * cosf(th);
    const float li  = lam * sinf(th);
    const size_t base = (size_t)b * 4095;

    // 1) load the LEAVES finalized child states (level root+E)
    float vr[LEAVES], vi[LEAVES];
    {
        const int nbL = ((rs + 1) << E) - 1;
#pragma unroll
        for (int i = 0; i < LEAVES; ++i) {
            const size_t r = (base + nbL + i) * 512;
            vr[i] = b2f(buf[r + c]);
            vi[i] = b2f(buf[r + 256 + c]);
        }
    }
    // 2) load ALL gamma*in values for the nodes to be computed (independent)
    float gr[LEAVES - 1], gi[LEAVES - 1];
    {
        int idx = 0;
#pragma unroll
        for (int e = E - 1; e >= 0; --e) {
            const int n  = 1 << e;
            const int nb = ((rs + 1) << e) - 1;
#pragma unroll
            for (int i = 0; i < n; ++i) {
                const size_t r = (base + nb + i) * 512;
                gr[idx] = b2f(buf[r + c]);
                gi[idx] = b2f(buf[r + 256 + c]);
                ++idx;
            }
        }
    }
    // 3) compute bottom-up in registers; store each h once
    {
        int idx = 0;
#pragma unroll
        for (int e = E - 1; e >= 0; --e) {
            const int n  = 1 << e;
            const int nb = ((rs + 1) << e) - 1;
#pragma unroll
            for (int i = 0; i < n; ++i) {
                const float cr = vr[2 * i] + vr[2 * i + 1];
                const float ci = vi[2 * i] + vi[2 * i + 1];
                const float hr = lr * cr - li * ci + gr[idx];
                const float hi = lr * ci + li * cr + gi[idx];
                ++idx;
                const size_t r = (base + nb + i) * 512;
                buf[r + c]       = f2bf(hr);
                buf[r + 256 + c] = f2bf(hi);
                vr[i] = hr;
                vi[i] = hi;
            }
        }
    }
}

extern "C" void kernel_launch(void* const* d_in, const int* in_sizes, int n_in,
                              void* d_out, int out_size, void* d_ws, size_t ws_size,
                              hipStream_t stream) {
    const float* x         = (const float*)d_in[0];
    const float* W_in      = (const float*)d_in[2];
    const float* b_in      = (const float*)d_in[3];
    const float* nu_log    = (const float*)d_in[4];
    const float* theta_log = (const float*)d_in[5];
    const float* gamma_log = (const float*)d_in[6];
    const float* B_re      = (const float*)d_in[7];
    const float* B_im      = (const float*)d_in[8];
    const float* C_re      = (const float*)d_in[9];
    const float* C_im      = (const float*)d_in[10];
    float* out = (float*)d_out;

    char* ws = (char*)d_ws;
    const size_t HB = (size_t)ROWS * 512 * 2;   // 67,092,480 bytes
    unsigned short* x16   = (unsigned short*)ws;
    unsigned short* hb16  = (unsigned short*)(ws + HB);
    unsigned short* M16   = (unsigned short*)(ws + 2 * HB);
    unsigned short* C16   = (unsigned short*)(ws + 2 * HB + 512 * 512 * 2);
    float*          biasc = (float*)(ws + 2 * HB + 2 * 512 * 512 * 2);

    prep_all<<<PREP_GRID, 256, 0, stream>>>(x, x16, W_in, B_re, B_im, gamma_log,
                                            M16, b_in, biasc, C_re, C_im, C16);

    gemm_mfma<true><<<2048, 256, 0, stream>>>(x16, M16, biasc, hb16, ROWS);

    // levels 10..7 (roots at level 7: nodes 127..254), then 6..3 (roots at
    // level 3: nodes 7..14), then 2..0 (root 0).
    tree_up<4><<<dim3(16, 128), 256, 0, stream>>>(hb16, nu_log, theta_log, 127);
    tree_up<4><<<dim3(16, 8),   256, 0, stream>>>(hb16, nu_log, theta_log, 7);
    tree_up<3><<<dim3(16, 1),   256, 0, stream>>>(hb16, nu_log, theta_log, 0);

    gemm_mfma<false><<<2048, 256, 0, stream>>>(hb16, C16, nullptr, out, ROWS);
}

// Round 2
// 399.864 us; speedup vs baseline: 1.0566x; 1.0342x over previous
//
#include <hip/hip_runtime.h>

// TreeLRU: B=16, N=4095 heap, IN=OUT=512, S=256.
// Round 6: (1) prep_all reordered (prep_M/C/bias blocks first, cvt last) and
// cvt made grid-stride (2048 blocks, 16 float4/thread, unroll 4) -- round-1
// showed prep_all at 93us / 1.5 TB/s (latency-bound wave churn + prep_M tail).
// (2) tree_up -> tree_up2: VGPR_Count=32 proved the compiler sank the
// "up-front" loads into a 31-deep dependent latency chain. Now 2 channels per
// thread (packed uint loads, 256B/wave), 2 subtrees per block, and a
// sched_barrier(0) pinning all loads before the compute phase.
// (3) gemm: s_setprio(1) around MFMA cluster + hoisted stage base pointers.

#define ROWS 65520
#define KDIM 512

typedef __attribute__((ext_vector_type(8))) short bf16x8;
typedef __attribute__((ext_vector_type(4))) float f32x4;

__device__ __forceinline__ unsigned short f2bf(float f) {
    unsigned int u = __float_as_uint(f);
    unsigned int r = (u + 0x7FFFu + ((u >> 16) & 1u)) >> 16;
    return (unsigned short)r;
}
__device__ __forceinline__ float b2f(unsigned short h) {
    return __uint_as_float(((unsigned int)h) << 16);
}
__device__ __forceinline__ float b2f_lo(unsigned int p) {      // low bf16 of pair
    return __uint_as_float(p << 16);
}
__device__ __forceinline__ float b2f_hi(unsigned int p) {      // high bf16 of pair
    return __uint_as_float(p & 0xFFFF0000u);
}

// ---------------- merged prep: prep_M | prep_C | prep_bias | cvt ----------------
// prep_M:   blocks [0, 1024)      M = (Bsel * gamma) @ W, f32 math, bf16 out
// prep_C:   blocks [1024, 2048)   C16 = [Cre | -Cim] bf16
// prep_bias:blocks [2048, 2176)   biasc[c] = gamma_c * <b_in, Bsel_c>, 4 ch/block
// cvt:      blocks [2176, 4224)   x f32 -> bf16, grid-stride, 16 float4/thread
#define PC_BASE   1024
#define PB_BASE   2048
#define CVT_BASE  2176
#define CVT_BLKS  2048
#define PREP_GRID 4224
#define CVT_N4    8386560          // ROWS*512/4

__global__ __launch_bounds__(256) void prep_all(const float* __restrict__ x,
                                                unsigned short* __restrict__ x16,
                                                const float* __restrict__ W,
                                                const float* __restrict__ Bre,
                                                const float* __restrict__ Bim,
                                                const float* __restrict__ gamma_log,
                                                unsigned short* __restrict__ M16,
                                                const float* __restrict__ bin,
                                                float* __restrict__ biasc,
                                                const float* __restrict__ Cre,
                                                const float* __restrict__ Cim,
                                                unsigned short* __restrict__ C16) {
    __shared__ float Bs[16][17];
    __shared__ float Ws[16][17];
    const int blk = blockIdx.x;
    const int t = threadIdx.x;

    if (blk < PC_BASE) {
        // ---- prep_M: 32x32 grid of 16x16 tiles ----
        const int bx = blk & 31;       // j tile
        const int by = blk >> 5;       // cc tile
        const int tx = t & 15;
        const int ty = t >> 4;
        const int j  = bx * 16 + tx;
        const int cc = by * 16 + ty;
        const float* Bsel = (cc < 256) ? (Bre + (size_t)cc * 512)
                                       : (Bim + (size_t)(cc - 256) * 512);
        float acc = 0.f;
        for (int kt = 0; kt < 512; kt += 16) {
            Bs[ty][tx] = Bsel[kt + tx];
            Ws[ty][tx] = W[(size_t)(kt + ty) * 512 + j];
            __syncthreads();
#pragma unroll
            for (int k = 0; k < 16; ++k) acc += Bs[ty][k] * Ws[k][tx];
            __syncthreads();
        }
        float g = expf(gamma_log[cc & 255]);
        M16[(size_t)cc * 512 + j] = f2bf(acc * g);
    } else if (blk < PB_BASE) {
        // ---- prep_C ----
        int idx = (blk - PC_BASE) * 256 + t;   // 0..262143
        int o = idx >> 9;
        int s = idx & 511;
        float v = (s < 256) ? Cre[(size_t)o * 256 + s] : -Cim[(size_t)o * 256 + (s - 256)];
        C16[idx] = f2bf(v);
    } else if (blk < CVT_BASE) {
        // ---- prep_bias: 4 channels per block, one wave each ----
        const int c = (blk - PB_BASE) * 4 + (t >> 6);   // 0..511
        const int lane = t & 63;
        const float* Bsel = (c < 256) ? (Bre + (size_t)c * 512)
                                      : (Bim + (size_t)(c - 256) * 512);
        float acc = 0.f;
#pragma unroll
        for (int i = lane; i < 512; i += 64) acc += bin[i] * Bsel[i];
#pragma unroll
        for (int off = 32; off > 0; off >>= 1) acc += __shfl_down(acc, off, 64);
        if (lane == 0) biasc[c] = acc * expf(gamma_log[c & 255]);
    } else {
        // ---- cvt f32 -> bf16, grid-stride: 16 float4 per thread ----
        int i = (blk - CVT_BASE) * 256 + t;
#pragma unroll 4
        for (; i < CVT_N4; i += CVT_BLKS * 256) {
            float4 v = ((const float4*)x)[i];
            ushort4 o;
            o.x = f2bf(v.x); o.y = f2bf(v.y); o.z = f2bf(v.z); o.w = f2bf(v.w);
            ((ushort4*)x16)[i] = o;
        }
    }
}

// ---------------- bf16 MFMA GEMM: C = A @ B^T (+bias), K=N=512 ----------------
// 128x128 block tile, 4 waves, each wave 64x64 (4x4 of 16x16x32 MFMA), BK=64.
// Double-buffered LDS (2x32KB): iteration t prefetches tile t+1 into buf^1
// while the MFMAs consume buf. __syncthreads at the bottom of each iter
// supplies the vmcnt(0)+lgkmcnt(0)+s_barrier that publishes the prefetch.
// XCD-aware swizzle: xcd = bid&7; each XCD owns 64 row-tiles x 4 col-tiles
// with the 4 A-sharing siblings adjacent in dispatch order (A L2-shared).
template <bool OUT_BF16>
__global__ __launch_bounds__(256) void gemm_mfma(const unsigned short* __restrict__ A,
                                                 const unsigned short* __restrict__ Bm,
                                                 const float* __restrict__ bias,
                                                 void* __restrict__ Cout,
                                                 int Mrows) {
    __shared__ __align__(16) unsigned short As[2][128 * 64];
    __shared__ __align__(16) unsigned short Bs[2][128 * 64];
    const int t = threadIdx.x;
    const int lane = t & 63;
    const int w = t >> 6;
    const int wr = (w >> 1) * 64;
    const int wc = (w & 1) * 64;
    const int bid = blockIdx.x;
    const int xcd = bid & 7;
    const int lid = bid >> 3;               // 0..255
    const int rowblk = xcd * 64 + (lid >> 2);
    const int colblk = lid & 3;
    const int row0 = rowblk * 128;
    const int col0 = colblk * 128;
    const int kt0  = (rowblk & 7) * 64;

    f32x4 acc[4][4] = {};

    // hoisted per-thread stage bases (row/kg swizzle is iter-invariant)
    const unsigned short* gaB[4];
    const unsigned short* gbB[4];
    int ldsoff[4];
#pragma unroll
    for (int q = 0; q < 4; ++q) {
        int c_   = q * 256 + t;            // chunk id 0..1023
        int row_ = c_ >> 3;
        int kc_  = c_ & 7;
        int kg_  = kc_ ^ (row_ & 7);
        int ar_  = row0 + row_; if (ar_ >= Mrows) ar_ = Mrows - 1;
        gaB[q] = A + (size_t)ar_ * KDIM + kg_ * 8;
        gbB[q] = Bm + (size_t)(col0 + row_) * KDIM + kg_ * 8;
        ldsoff[q] = c_ * 8;
    }

#define STAGE(pb, itv)                                                         \
    do {                                                                       \
        const int kt_ = (kt0 + (itv) * 64) & 511;                              \
        _Pragma("unroll")                                                      \
        for (int q = 0; q < 4; ++q) {                                          \
            __builtin_amdgcn_global_load_lds(                                  \
                (const __attribute__((address_space(1))) unsigned int*)(gaB[q] + kt_),\
                (__attribute__((address_space(3))) unsigned int*)(&As[pb][ldsoff[q]]),\
                16, 0, 0);                                                     \
            __builtin_amdgcn_global_load_lds(                                  \
                (const __attribute__((address_space(1))) unsigned int*)(gbB[q] + kt_),\
                (__attribute__((address_space(3))) unsigned int*)(&Bs[pb][ldsoff[q]]),\
                16, 0, 0);                                                     \
        }                                                                      \
    } while (0)

    STAGE(0, 0);
    __syncthreads();        // drains vmcnt(0): tile 0 resident

    int cur = 0;
    for (int it = 0; it < 8; ++it) {
        if (it < 7) STAGE(cur ^ 1, it + 1);   // prefetch next tile (overlaps MFMA)
        __builtin_amdgcn_s_setprio(1);
#pragma unroll
        for (int kk = 0; kk < 64; kk += 32) {
            const int kgc = kk >> 3;  // 0 or 4
            bf16x8 af[4], bfr[4];
#pragma unroll
            for (int i = 0; i < 4; ++i) {
                int row = wr + i * 16 + (lane & 15);
                int kca = (kgc + (lane >> 4)) ^ (row & 7);
                af[i] = *(const bf16x8*)(&As[cur][row * 64 + kca * 8]);
                int colr = wc + i * 16 + (lane & 15);
                int kcb = (kgc + (lane >> 4)) ^ (colr & 7);
                bfr[i] = *(const bf16x8*)(&Bs[cur][colr * 64 + kcb * 8]);
            }
#pragma unroll
            for (int i = 0; i < 4; ++i)
#pragma unroll
                for (int j = 0; j < 4; ++j)
                    acc[i][j] = __builtin_amdgcn_mfma_f32_16x16x32_bf16(
                        af[i], bfr[j], acc[i][j], 0, 0, 0);
        }
        __builtin_amdgcn_s_setprio(0);
        __syncthreads();    // vmcnt(0)+barrier: publishes prefetched tile
        cur ^= 1;
    }
#undef STAGE

    // epilogue: C/D layout col=lane&15, row=(lane>>4)*4+reg  [m89/m91 verified]
    const int cq = lane >> 4;
    const int cl = lane & 15;
#pragma unroll
    for (int i = 0; i < 4; ++i) {
#pragma unroll
        for (int j = 0; j < 4; ++j) {
#pragma unroll
            for (int r = 0; r < 4; ++r) {
                int grow = row0 + wr + i * 16 + cq * 4 + r;
                int gcol = col0 + wc + j * 16 + cl;
                if (grow < Mrows) {
                    float v = acc[i][j][r];
                    if (bias) v += bias[gcol];
                    if (OUT_BF16)
                        ((unsigned short*)Cout)[(size_t)grow * 512 + gcol] = f2bf(v);
                    else
                        ((float*)Cout)[(size_t)grow * 512 + gcol] = v;
                }
            }
        }
    }
}

// ---------------- tree recurrence, v2 ----------------
// Block = 256 threads = 2 half-blocks of 128; half h handles subtree
// rs = root_base + 2*blockIdx.y + h. Thread j owns channels 2j, 2j+1 (packed
// uint loads/stores: 4B/lane, 256B/wave). All loads issued before a
// sched_barrier(0) so the compiler cannot sink them into the dependent
// compute chain (round-1 VGPR_Count=32 proved it did exactly that).
template <int E>
__global__ __launch_bounds__(256) void tree_up2(unsigned short* __restrict__ buf,
                                                const float* __restrict__ nu_log,
                                                const float* __restrict__ theta_log,
                                                int root_base, int nroots) {
    const int b = blockIdx.x;
    const int h = threadIdx.x >> 7;
    const int j2 = (threadIdx.x & 127) * 2;        // channel pair base
    const int rr = blockIdx.y * 2 + h;
    if (rr >= nroots) return;
    const int rs = root_base + rr;
    constexpr int LEAVES = 1 << E;
    constexpr int NODES = LEAVES - 1;

    float lr0, li0, lr1, li1;
    { const float lam = expf(-expf(nu_log[j2]));     const float th = expf(theta_log[j2]);
      lr0 = lam * cosf(th); li0 = lam * sinf(th); }
    { const float lam = expf(-expf(nu_log[j2 + 1])); const float th = expf(theta_log[j2 + 1]);
      lr1 = lam * cosf(th); li1 = lam * sinf(th); }
    const size_t base = (size_t)b * 4095;

    // 1) issue ALL loads (62 x 4B per thread, independent) ...
    unsigned int pr[LEAVES], pi[LEAVES];
    const int nbL = ((rs + 1) << E) - 1;
#pragma unroll
    for (int i = 0; i < LEAVES; ++i) {
        const size_t r = (base + nbL + i) * 512;
        pr[i] = *(const unsigned int*)(buf + r + j2);
        pi[i] = *(const unsigned int*)(buf + r + 256 + j2);
    }
    unsigned int qr[NODES], qi[NODES];
#pragma unroll
    for (int e = E - 1; e >= 0; --e) {
#pragma unroll
        for (int i = 0; i < (1 << e); ++i) {
            const int idx = LEAVES - (2 << e) + i;
            const size_t r = (base + (((rs + 1) << e) - 1) + i) * 512;
            qr[idx] = *(const unsigned int*)(buf + r + j2);
            qi[idx] = *(const unsigned int*)(buf + r + 256 + j2);
        }
    }
    // ... 2) and only then start consuming (pins MLP; prevents load sinking)
    __builtin_amdgcn_sched_barrier(0);

    float vr0[LEAVES], vi0[LEAVES], vr1[LEAVES], vi1[LEAVES];
#pragma unroll
    for (int i = 0; i < LEAVES; ++i) {
        vr0[i] = b2f_lo(pr[i]); vr1[i] = b2f_hi(pr[i]);
        vi0[i] = b2f_lo(pi[i]); vi1[i] = b2f_hi(pi[i]);
    }
#pragma unroll
    for (int e = E - 1; e >= 0; --e) {
#pragma unroll
        for (int i = 0; i < (1 << e); ++i) {
            const int idx = LEAVES - (2 << e) + i;
            const float cr0 = vr0[2 * i] + vr0[2 * i + 1];
            const float ci0 = vi0[2 * i] + vi0[2 * i + 1];
            const float cr1 = vr1[2 * i] + vr1[2 * i + 1];
            const float ci1 = vi1[2 * i] + vi1[2 * i + 1];
            const float hr0 = lr0 * cr0 - li0 * ci0 + b2f_lo(qr[idx]);
            const float hi0 = lr0 * ci0 + li0 * cr0 + b2f_lo(qi[idx]);
            const float hr1 = lr1 * cr1 - li1 * ci1 + b2f_hi(qr[idx]);
            const float hi1 = lr1 * ci1 + li1 * cr1 + b2f_hi(qi[idx]);
            const size_t r = (base + (((rs + 1) << e) - 1) + i) * 512;
            *(unsigned int*)(buf + r + j2) =
                (unsigned int)f2bf(hr0) | ((unsigned int)f2bf(hr1) << 16);
            *(unsigned int*)(buf + r + 256 + j2) =
                (unsigned int)f2bf(hi0) | ((unsigned int)f2bf(hi1) << 16);
            vr0[i] = hr0; vi0[i] = hi0; vr1[i] = hr1; vi1[i] = hi1;
        }
    }
}

extern "C" void kernel_launch(void* const* d_in, const int* in_sizes, int n_in,
                              void* d_out, int out_size, void* d_ws, size_t ws_size,
                              hipStream_t stream) {
    const float* x         = (const float*)d_in[0];
    const float* W_in      = (const float*)d_in[2];
    const float* b_in      = (const float*)d_in[3];
    const float* nu_log    = (const float*)d_in[4];
    const float* theta_log = (const float*)d_in[5];
    const float* gamma_log = (const float*)d_in[6];
    const float* B_re      = (const float*)d_in[7];
    const float* B_im      = (const float*)d_in[8];
    const float* C_re      = (const float*)d_in[9];
    const float* C_im      = (const float*)d_in[10];
    float* out = (float*)d_out;

    char* ws = (char*)d_ws;
    const size_t HB = (size_t)ROWS * 512 * 2;   // 67,092,480 bytes
    unsigned short* x16   = (unsigned short*)ws;
    unsigned short* hb16  = (unsigned short*)(ws + HB);
    unsigned short* M16   = (unsigned short*)(ws + 2 * HB);
    unsigned short* C16   = (unsigned short*)(ws + 2 * HB + 512 * 512 * 2);
    float*          biasc = (float*)(ws + 2 * HB + 2 * 512 * 512 * 2);

    prep_all<<<PREP_GRID, 256, 0, stream>>>(x, x16, W_in, B_re, B_im, gamma_log,
                                            M16, b_in, biasc, C_re, C_im, C16);

    gemm_mfma<true><<<2048, 256, 0, stream>>>(x16, M16, biasc, hb16, ROWS);

    // levels 10..7 (roots at level 7: nodes 127..254), then 6..3 (roots at
    // level 3: nodes 7..14), then 2..0 (root 0).
    tree_up2<4><<<dim3(16, 64), 256, 0, stream>>>(hb16, nu_log, theta_log, 127, 128);
    tree_up2<4><<<dim3(16, 4),  256, 0, stream>>>(hb16, nu_log, theta_log, 7, 8);
    tree_up2<3><<<dim3(16, 1),  256, 0, stream>>>(hb16, nu_log, theta_log, 0, 1);

    gemm_mfma<false><<<2048, 256, 0, stream>>>(hb16, C16, nullptr, out, ROWS);
}